// Round 14
// baseline (116.581 us; speedup 1.0000x reference)
//
#include <hip/hip_runtime.h>

typedef unsigned short u16;
typedef unsigned int u32;
typedef __attribute__((ext_vector_type(8))) short bf16x8;
typedef __attribute__((ext_vector_type(4))) short bf16x4;
typedef __attribute__((ext_vector_type(4))) float f32x4;
typedef __attribute__((ext_vector_type(4))) unsigned short u16x4;
typedef __attribute__((ext_vector_type(2))) unsigned int u32x2;

// B=2, T=2048, E=768, H=12, HD=64
#define GM 4096   // B*T
#define GN 768
#define GK 768
#define QSCALE 0.18033688011112042f   // 0.125 * log2(e), folded into Q

#define HAS_MFMA16 __has_builtin(__builtin_amdgcn_mfma_f32_16x16x16bf16_1k)

static __device__ __forceinline__ u16 f2bf(float f) {
  union { float f; unsigned u; } v; v.f = f;
  unsigned u = v.u;
  return (u16)((u + 0x7FFFu + ((u >> 16) & 1u)) >> 16);
}

static __device__ __forceinline__ float exp2_hw(float x) {
  float r;
  asm("v_exp_f32 %0, %1" : "=v"(r) : "v"(x));
  return r;
}

// pack two floats to bf16 pair (round-half-up), low half = lo
static __device__ __forceinline__ u32 pack_rn(float lo, float hi) {
  u32 a = __float_as_uint(lo) + 0x8000u;
  u32 b = __float_as_uint(hi) + 0x8000u;
  return (a >> 16) | (b & 0xFFFF0000u);
}

static __device__ __forceinline__ void gld16(const void* g, void* l) {
  __builtin_amdgcn_global_load_lds((__attribute__((address_space(1))) void*)(g),
                                   (__attribute__((address_space(3))) void*)(l),
                                   16, 0, 0);
}

// ---------------- fp32 -> bf16 convert, all 5 matrices in one launch ----------------
__global__ void cvt_all(const float* __restrict__ x,
                        const float* __restrict__ w0, const float* __restrict__ w1,
                        const float* __restrict__ w2, const float* __restrict__ w3,
                        u16* __restrict__ xo,
                        u16* __restrict__ o0, u16* __restrict__ o1,
                        u16* __restrict__ o2, u16* __restrict__ o3) {
  int blk = blockIdx.x;
  const float* in; u16* out; int base;
  if (blk < 3072) { in = x; out = xo; base = 0; }
  else {
    int wsel = (blk - 3072) / 576;
    base = 3072 + wsel * 576;
    in = wsel == 0 ? w0 : (wsel == 1 ? w1 : (wsel == 2 ? w2 : w3));
    out = wsel == 0 ? o0 : (wsel == 1 ? o1 : (wsel == 2 ? o2 : o3));
  }
  int i = (blk - base) * 256 + threadIdx.x;
  float4 v = ((const float4*)in)[i];
  u16x4 o;
  o[0] = f2bf(v.x); o[1] = f2bf(v.y); o[2] = f2bf(v.z); o[3] = f2bf(v.w);
  ((u16x4*)out)[i] = o;
}

// ---------------- GEMM: C = scale * A(MxK) * Bt(NxK)^T ----------------
// MODE 0: bf16 C[row][col]. MODE 1: f32 C[row][col]. MODE 2: V -> per-head
// transposed VT using the RESHAPE head split: flat = row*768+col = bh*131072 +
// t*64 + d  (u = row*12 + col/64; bh = u>>11; t = u&2047; d = col&63);
// store VT[bh][d][t]. Element-identical to the old vtrans(MODE0) pipeline.
template<int MODE>
static __device__ __forceinline__ void gemm_core(const u16* __restrict__ A,
                                                 const u16* __restrict__ B,
                                                 void* __restrict__ O,
                                                 u16* lA, u16* lB, float scale)
{
  const int tid = threadIdx.x;
  const int wave = tid >> 6, lane = tid & 63;
  const int g = lane >> 4, c = lane & 15;
  const int wr = (wave >> 1) * 64, wc = (wave & 1) * 64;
  const int tm = blockIdx.x * 128, tn = blockIdx.y * 128;

  f32x4 acc[4][4] = {};

  const int srow = lane >> 2;
  const int scolb = (lane & 3) * 16;
  const char* gA = (const char*)(A + (size_t)tm * GK);
  const char* gB = (const char*)(B + (size_t)tn * GK);

  for (int k0 = 0; k0 < GK; k0 += 32) {
#pragma unroll
    for (int i = 0; i < 2; ++i) {
      const int chunk = wave * 2 + i;
      const int row = chunk * 16 + srow;
      gld16(gA + (size_t)row * (GK * 2) + k0 * 2 + scolb, (char*)lA + chunk * 1024);
      gld16(gB + (size_t)row * (GK * 2) + k0 * 2 + scolb, (char*)lB + chunk * 1024);
    }
    __syncthreads();
    bf16x8 af[4], bfr[4];
#pragma unroll
    for (int m = 0; m < 4; ++m)
      af[m] = *(const bf16x8*)((const char*)lA + (wr + m * 16 + c) * 64 + g * 16);
#pragma unroll
    for (int n = 0; n < 4; ++n)
      bfr[n] = *(const bf16x8*)((const char*)lB + (wc + n * 16 + c) * 64 + g * 16);
#pragma unroll
    for (int m = 0; m < 4; ++m)
#pragma unroll
      for (int n = 0; n < 4; ++n)
        acc[m][n] = __builtin_amdgcn_mfma_f32_16x16x32_bf16(af[m], bfr[n], acc[m][n], 0, 0, 0);
    __syncthreads();
  }

#pragma unroll
  for (int m = 0; m < 4; ++m)
#pragma unroll
    for (int n = 0; n < 4; ++n) {
      const int row0 = tm + wr + m * 16 + g * 4;
      const int col = tn + wc + n * 16 + c;
      if (MODE == 2) {
        const int d = col & 63;
        const int cq = col >> 6;
#pragma unroll
        for (int r = 0; r < 4; ++r) {
          const int u = (row0 + r) * 12 + cq;
          ((u16*)O)[(size_t)(u >> 11) * 131072 + (size_t)d * 2048 + (u & 2047)] =
              f2bf(acc[m][n][r]);
        }
      } else {
#pragma unroll
        for (int r = 0; r < 4; ++r) {
          if (MODE == 1)
            ((float*)O)[(size_t)(row0 + r) * GN + col] = acc[m][n][r];
          else
            ((u16*)O)[(size_t)(row0 + r) * GN + col] = f2bf(acc[m][n][r] * scale);
        }
      }
    }
}

__global__ __launch_bounds__(256) void gemm_qkv(const u16* __restrict__ A,
    const u16* __restrict__ B0, const u16* __restrict__ B1, const u16* __restrict__ B2,
    u16* __restrict__ O0, u16* __restrict__ O1, u16* __restrict__ VT)
{
  __shared__ u16 lA[4096], lB[4096];
  if (blockIdx.z == 0)      gemm_core<0>(A, B0, O0, lA, lB, QSCALE);  // Q (pre-scaled)
  else if (blockIdx.z == 1) gemm_core<0>(A, B1, O1, lA, lB, 1.0f);    // K
  else                      gemm_core<2>(A, B2, VT, lA, lB, 1.0f);    // V -> VT direct
}

__global__ __launch_bounds__(256) void gemm_pool(const u16* __restrict__ A,
    const u16* __restrict__ B, float* __restrict__ O)
{
  __shared__ u16 lA[4096], lB[4096];
  gemm_core<1>(A, B, O, lA, lB, 1.0f);
}

// ---------------- flash attention: R11 (static grid, x16-PV, register P) ----------------
static __device__ __forceinline__ void stage_tile(const char* gbase, int rowstride,
                                                  char* lbuf, int wave, int lane) {
#pragma unroll
  for (int i = 0; i < 2; ++i) {
    const int chunk = i * 256 + wave * 64 + lane;
    const int row = chunk >> 3;
    const int colb = (chunk & 7) << 4;
    const char* src = gbase + (size_t)row * rowstride + (colb ^ ((row & 7) << 4));
    char* dst = lbuf + i * 4096 + wave * 1024;
    gld16(src, dst);
  }
}

__global__ __launch_bounds__(256) void attn(const u16* __restrict__ Q,
                                            const u16* __restrict__ Km,
                                            const u16* __restrict__ VT,
                                            u16* __restrict__ X2)
{
  const int qblk = blockIdx.x;
  const int bh = blockIdx.y;
  const int b = bh / 12, h = bh % 12;
  const int tid = threadIdx.x, wave = tid >> 6, lane = tid & 63;
  const int g = lane >> 4, c = lane & 15;
  const int swr = (c & 7) << 4;                   // K/V tile read swizzle (row = *16+c)
  const int swz = ((c & 7) ^ (c >> 3)) << 4;      // P tile swizzle (fallback only)

  __shared__ char Kl[2][8192];
  __shared__ char Vl[2][8192];
#if !HAS_MFMA16
  __shared__ u16 Plds[4][1024];
  u16* pl = Plds[wave];
#endif
  (void)swz;

  const char* Khb = (const char*)(Km + (size_t)bh * 131072);
  const char* Vhb = (const char*)(VT + (size_t)bh * 131072);   // [64][2048] u16
  const u16* Qh = Q + (size_t)bh * 131072;

  const int q0 = qblk * 64 + wave * 16;
  const int nkt = qblk + 1;

  stage_tile(Khb, 128, Kl[0], wave, lane);
  stage_tile(Vhb, 4096, Vl[0], wave, lane);

  bf16x8 qf[2];
#pragma unroll
  for (int kk = 0; kk < 2; ++kk)
    qf[kk] = *(const bf16x8*)(Qh + (size_t)(q0 + c) * 64 + kk * 32 + g * 8);

  f32x4 oacc[4] = {};
  float lsum = 0.f;

  __syncthreads();   // tile 0 staged (vmcnt drained before barrier)

  for (int kt = 0; kt < nkt; ++kt) {
    const int cur = kt & 1;
    if (kt + 1 < nkt) {
      stage_tile(Khb + (size_t)(kt + 1) * 8192, 128, Kl[cur ^ 1], wave, lane);
      stage_tile(Vhb + (size_t)(kt + 1) * 128, 4096, Vl[cur ^ 1], wave, lane);
    }
    // S^T = K Q^T : D[key][qrow]  (key = n*16 + g*4 + r lane-local, qrow = c)
    f32x4 s[4] = {};
    __builtin_amdgcn_s_setprio(1);
#pragma unroll
    for (int kk = 0; kk < 2; ++kk)
#pragma unroll
      for (int n = 0; n < 4; ++n) {
        bf16x8 kf = *(const bf16x8*)(Kl[cur] + (size_t)(n * 16 + c) * 128 + ((kk * 64 + g * 16) ^ swr));
        s[n] = __builtin_amdgcn_mfma_f32_16x16x32_bf16(kf, qf[kk], s[n], 0, 0, 0);
      }
    __builtin_amdgcn_s_setprio(0);

#if HAS_MFMA16
    // p = 2^s -> bf16x4 A-fragments, entirely in registers
    bf16x4 pa[4];
    if (kt == nkt - 1) {
      const int qrow = q0 + c;
#pragma unroll
      for (int n = 0; n < 4; ++n) {
        const int k0i = kt * 64 + n * 16 + g * 4;
        float p0 = (k0i + 0 > qrow) ? 0.f : exp2_hw(s[n][0]);
        float p1 = (k0i + 1 > qrow) ? 0.f : exp2_hw(s[n][1]);
        float p2 = (k0i + 2 > qrow) ? 0.f : exp2_hw(s[n][2]);
        float p3 = (k0i + 3 > qrow) ? 0.f : exp2_hw(s[n][3]);
        lsum += (p0 + p1) + (p2 + p3);
        u32x2 pw; pw[0] = pack_rn(p0, p1); pw[1] = pack_rn(p2, p3);
        pa[n] = __builtin_bit_cast(bf16x4, pw);
      }
    } else {
#pragma unroll
      for (int n = 0; n < 4; ++n) {
        float p0 = exp2_hw(s[n][0]);
        float p1 = exp2_hw(s[n][1]);
        float p2 = exp2_hw(s[n][2]);
        float p3 = exp2_hw(s[n][3]);
        lsum += (p0 + p1) + (p2 + p3);
        u32x2 pw; pw[0] = pack_rn(p0, p1); pw[1] = pack_rn(p2, p3);
        pa[n] = __builtin_bit_cast(bf16x4, pw);
      }
    }
    // O += P V : 16 x 16x16x16 MFMA, V B-fragments (b64) from staged LDS tile
    __builtin_amdgcn_s_setprio(1);
#pragma unroll
    for (int n = 0; n < 4; ++n)
#pragma unroll
      for (int nn = 0; nn < 4; ++nn) {
        bf16x4 vb = *(const bf16x4*)(Vl[cur] + (size_t)(nn * 16 + c) * 128 + ((n * 32 + g * 8) ^ swr));
        oacc[nn] = __builtin_amdgcn_mfma_f32_16x16x16bf16_1k(pa[n], vb, oacc[nn], 0, 0, 0);
      }
    __builtin_amdgcn_s_setprio(0);
#else
    // fallback: P-LDS path
    if (kt == nkt - 1) {
      const int qrow = q0 + c;
#pragma unroll
      for (int n = 0; n < 4; ++n) {
        const int k0i = kt * 64 + n * 16 + g * 4;
        float p0 = (k0i + 0 > qrow) ? 0.f : exp2_hw(s[n][0]);
        float p1 = (k0i + 1 > qrow) ? 0.f : exp2_hw(s[n][1]);
        float p2 = (k0i + 2 > qrow) ? 0.f : exp2_hw(s[n][2]);
        float p3 = (k0i + 3 > qrow) ? 0.f : exp2_hw(s[n][3]);
        lsum += (p0 + p1) + (p2 + p3);
        u32x2 pw; pw[0] = pack_rn(p0, p1); pw[1] = pack_rn(p2, p3);
        *(u32x2*)((char*)pl + c * 128 + ((n * 32 + g * 8) ^ swz)) = pw;
      }
    } else {
#pragma unroll
      for (int n = 0; n < 4; ++n) {
        float p0 = exp2_hw(s[n][0]);
        float p1 = exp2_hw(s[n][1]);
        float p2 = exp2_hw(s[n][2]);
        float p3 = exp2_hw(s[n][3]);
        lsum += (p0 + p1) + (p2 + p3);
        u32x2 pw; pw[0] = pack_rn(p0, p1); pw[1] = pack_rn(p2, p3);
        *(u32x2*)((char*)pl + c * 128 + ((n * 32 + g * 8) ^ swz)) = pw;
      }
    }
    __builtin_amdgcn_s_setprio(1);
#pragma unroll
    for (int kk = 0; kk < 2; ++kk) {
      bf16x8 pab = *(const bf16x8*)((const char*)pl + c * 128 + ((kk * 64 + g * 16) ^ swz));
#pragma unroll
      for (int n = 0; n < 4; ++n) {
        bf16x8 vfb = *(const bf16x8*)(Vl[cur] + (size_t)(n * 16 + c) * 128 + ((kk * 64 + g * 16) ^ swr));
        oacc[n] = __builtin_amdgcn_mfma_f32_16x16x32_bf16(pab, vfb, oacc[n], 0, 0, 0);
      }
    }
    __builtin_amdgcn_s_setprio(0);
#endif
    __syncthreads();
  }

  // epilogue: reduce lsum across the 4 lanes sharing qrow c, broadcast, normalize
  float tot = lsum;
  tot += __shfl_xor(tot, 16);
  tot += __shfl_xor(tot, 32);
  float linv[4];
#pragma unroll
  for (int r = 0; r < 4; ++r)
    linv[r] = __frcp_rn(__shfl(tot, g * 4 + r));
#pragma unroll
  for (int n = 0; n < 4; ++n)
#pragma unroll
    for (int r = 0; r < 4; ++r) {
      const float o = oacc[n][r] * linv[r];
      const int t = q0 + g * 4 + r;
      X2[((size_t)b * 2048 + t) * 768 + h * 64 + n * 16 + c] = f2bf(o);
    }
}

// ---------------- host ----------------
extern "C" void kernel_launch(void* const* d_in, const int* in_sizes, int n_in,
                              void* d_out, int out_size, void* d_ws, size_t ws_size,
                              hipStream_t stream) {
  const float* x  = (const float*)d_in[0];
  const float* wq = (const float*)d_in[1];
  const float* wk = (const float*)d_in[2];
  const float* wv = (const float*)d_in[3];
  const float* wp = (const float*)d_in[4];

  const size_t SZ_X = (size_t)GM * GN * 2;
  const size_t SZ_W = (size_t)GK * GN * 2;
  char* ws = (char*)d_ws;
  u16* xbf  = (u16*)(ws);
  u16* wqb  = (u16*)(ws + SZ_X);
  u16* wkb  = (u16*)(ws + SZ_X + SZ_W);
  u16* wvb  = (u16*)(ws + SZ_X + 2 * SZ_W);
  u16* wpb  = (u16*)(ws + SZ_X + 3 * SZ_W);
  u16* Qb   = (u16*)(ws + SZ_X + 4 * SZ_W);
  u16* Kb   = (u16*)(ws + 2 * SZ_X + 4 * SZ_W);
  u16* VT   = (u16*)(ws + 3 * SZ_X + 4 * SZ_W);
  u16* X2   = (u16*)(ws + 4 * SZ_X + 4 * SZ_W);
  if (ws_size < 5 * SZ_X + 4 * SZ_W) return;

  cvt_all<<<dim3(3072 + 4 * 576), dim3(256), 0, stream>>>(x, wq, wk, wv, wp,
                                                          xbf, wqb, wkb, wvb, wpb);
  gemm_qkv<<<dim3(32, 6, 3), dim3(256), 0, stream>>>(xbf, wqb, wkb, wvb, Qb, Kb, VT);
  attn<<<dim3(32, 24), dim3(256), 0, stream>>>(Qb, Kb, VT, X2);
  gemm_pool<<<dim3(32, 6), dim3(256), 0, stream>>>(X2, wpb, (float*)d_out);
}